// Round 2
// baseline (987.890 us; speedup 1.0000x reference)
//
#include <hip/hip_runtime.h>
#include <hip/hip_bf16.h>

// Problem constants (AttentionHead: B=4, T=2048, C=1024, hs=64). All fp32.
#define D_MODEL 1024
#define HS 64
#define T_LEN 2048

// ---------------------------------------------------------------------------
// Kernel 1: QKV projection. One block per token row (B*T rows).
// x-row staged in LDS; threads 0..191 each compute one of q/k/v[h].
// ---------------------------------------------------------------------------
__global__ __launch_bounds__(256) void qkv_kernel(
    const float* __restrict__ x,
    const float* __restrict__ Wq,
    const float* __restrict__ bq,
    const float* __restrict__ Wk,
    const float* __restrict__ bk,
    const float* __restrict__ Wv,
    float* __restrict__ q, float* __restrict__ k, float* __restrict__ v)
{
    __shared__ float xs[D_MODEL];
    const int row = blockIdx.x;
    const float* xr = x + (size_t)row * D_MODEL;
    for (int i = threadIdx.x; i < D_MODEL; i += 256)
        xs[i] = xr[i];
    __syncthreads();

    const int tid = threadIdx.x;
    if (tid < 192) {
        const int which = tid >> 6;   // 0=q, 1=k, 2=v
        const int h = tid & 63;
        const float* W = (which == 0) ? Wq : (which == 1) ? Wk : Wv;
        float acc = 0.f;
        #pragma unroll 8
        for (int c = 0; c < D_MODEL; ++c)
            acc = fmaf(xs[c], W[c * HS + h], acc);
        if (which == 0)      acc += bq[h];
        else if (which == 1) acc += bk[h];
        float* dst = (which == 0) ? q : (which == 1) ? k : v;
        dst[(size_t)row * HS + h] = acc;
    }
}

// ---------------------------------------------------------------------------
// Kernel 2: attention for one query row per block.
// scores (<=T) in LDS; two-pass softmax; PV with 4-way split over j.
// Scale is *sqrt(hs) = *8 (faithful to the reference).
// ---------------------------------------------------------------------------
__global__ __launch_bounds__(256) void attn_kernel(
    const float* __restrict__ q, const float* __restrict__ k,
    const float* __restrict__ v, const int* __restrict__ maskp,
    float* __restrict__ out, int T)
{
    __shared__ float sc[T_LEN];
    __shared__ __align__(16) float qs[HS];
    __shared__ float red[256];

    const int row = blockIdx.x;      // b*T + t
    const int b = row / T;
    const int t = row - b * T;
    const int tid = threadIdx.x;
    const int n = (*maskp != 0) ? (t + 1) : T;

    if (tid < HS) qs[tid] = q[(size_t)row * HS + tid];
    __syncthreads();

    const float* kb = k + (size_t)b * T * HS;
    const float* vb = v + (size_t)b * T * HS;
    const float4* qs4 = (const float4*)qs;

    // scores: s_j = 8 * dot(q_t, k_j) for j < n
    for (int j = tid; j < n; j += 256) {
        const float4* kj = (const float4*)(kb + (size_t)j * HS);
        float acc = 0.f;
        #pragma unroll
        for (int c = 0; c < HS / 4; ++c) {
            float4 kv = kj[c];
            float4 qv = qs4[c];
            acc = fmaf(qv.x, kv.x, acc);
            acc = fmaf(qv.y, kv.y, acc);
            acc = fmaf(qv.z, kv.z, acc);
            acc = fmaf(qv.w, kv.w, acc);
        }
        sc[j] = acc * 8.0f;
    }
    __syncthreads();

    // block max over sc[0..n)
    float m = -INFINITY;
    for (int j = tid; j < n; j += 256) m = fmaxf(m, sc[j]);
    red[tid] = m;
    __syncthreads();
    for (int off = 128; off > 0; off >>= 1) {
        if (tid < off) red[tid] = fmaxf(red[tid], red[tid + off]);
        __syncthreads();
    }
    m = red[0];
    __syncthreads();

    // exp + sum
    float l = 0.f;
    for (int j = tid; j < n; j += 256) {
        float e = __expf(sc[j] - m);
        sc[j] = e;
        l += e;
    }
    red[tid] = l;
    __syncthreads();
    for (int off = 128; off > 0; off >>= 1) {
        if (tid < off) red[tid] += red[tid + off];
        __syncthreads();
    }
    l = red[0];

    // PV: thread = (h, part); part strides over j by 4
    const int h = tid & 63;
    const int part = tid >> 6;
    float acc = 0.f;
    for (int j = part; j < n; j += 4)
        acc = fmaf(sc[j], vb[(size_t)j * HS + h], acc);
    __syncthreads();                 // all reads of red[0] done above
    red[tid] = acc;
    __syncthreads();
    if (tid < 64) {
        float o = (red[h] + red[h + 64] + red[h + 128] + red[h + 192]) / l;
        out[(size_t)row * HS + h] = o;
    }
}

// ---------------------------------------------------------------------------
extern "C" void kernel_launch(void* const* d_in, const int* in_sizes, int n_in,
                              void* d_out, int out_size, void* d_ws, size_t ws_size,
                              hipStream_t stream) {
    const float* x  = (const float*)d_in[0];
    const float* Wq = (const float*)d_in[1];
    const float* bq = (const float*)d_in[2];
    const float* Wk = (const float*)d_in[3];
    const float* bk = (const float*)d_in[4];
    const float* Wv = (const float*)d_in[5];
    const int* maskp = (const int*)d_in[6];

    const int BT = in_sizes[0] / D_MODEL;   // B*T = 8192
    const int T  = T_LEN;                   // 2048 per problem spec

    // fp32 q,k,v in workspace: 3 * BT * HS * 4 bytes = 6.3 MB
    float* q = (float*)d_ws;
    float* k = q + (size_t)BT * HS;
    float* v = k + (size_t)BT * HS;

    qkv_kernel<<<BT, 256, 0, stream>>>(x, Wq, bq, Wk, bk, Wv, q, k, v);
    attn_kernel<<<BT, 256, 0, stream>>>(q, k, v, maskp, (float*)d_out, T);
}

// Round 4
// 241.258 us; speedup vs baseline: 4.0947x; 4.0947x over previous
//
#include <hip/hip_runtime.h>
#include <hip/hip_bf16.h>

// AttentionHead: B=4, T=2048, C=1024, hs=64. All fp32.
#define D_MODEL 1024
#define HS 64
#define T_LEN 2048
#define JCH 512          // j-chunk width per attention block
#define NCH 4            // max chunks per row = T_LEN/JCH

// ---------------------------------------------------------------------------
// Kernel 1: QKV projection as a tiled GEMM: [BT x 1024] @ [1024 x 192].
// Block: 32 rows x 192 cols, 256 threads, K staged in chunks of 32.
// Thread: 2 rows x 12 cols = 24 fp32 accumulators.
// ---------------------------------------------------------------------------
__global__ __launch_bounds__(256) void qkv_kernel(
    const float* __restrict__ x,
    const float* __restrict__ Wq, const float* __restrict__ bq,
    const float* __restrict__ Wk, const float* __restrict__ bk,
    const float* __restrict__ Wv,
    float* __restrict__ q, float* __restrict__ k, float* __restrict__ v)
{
    __shared__ float xs[32][36];      // stride 36: 16B-aligned rows, conflict-free
    __shared__ float wt[32][196];     // cols 0..63=Wq, 64..127=Wk, 128..191=Wv

    const int r0  = blockIdx.x * 32;
    const int tid = threadIdx.x;
    const int tc  = tid & 15;         // col group: cols 12*tc .. 12*tc+11
    const int tr  = tid >> 4;         // row group: rows 2*tr, 2*tr+1

    float acc[2][12];
    #pragma unroll
    for (int i = 0; i < 2; ++i)
        #pragma unroll
        for (int j = 0; j < 12; ++j) acc[i][j] = 0.f;

    const int srow = tid >> 3;        // 0..31  staging row
    const int sc4  = tid & 7;         // 0..7   staging float4-col

    for (int k0 = 0; k0 < D_MODEL; k0 += 32) {
        __syncthreads();
        // stage x tile 32x32 (one float4/thread)
        *(float4*)&xs[srow][4 * sc4] =
            *(const float4*)(x + (size_t)(r0 + srow) * D_MODEL + k0 + 4 * sc4);
        // stage W tiles 32x64 each (TWO float4/thread/matrix — full 64 cols)
        {
            const size_t woff = (size_t)(k0 + srow) * HS;
            *(float4*)&wt[srow][0   + 4 * sc4]      = *(const float4*)(Wq + woff + 4 * sc4);
            *(float4*)&wt[srow][0   + 4 * sc4 + 32] = *(const float4*)(Wq + woff + 4 * sc4 + 32);
            *(float4*)&wt[srow][64  + 4 * sc4]      = *(const float4*)(Wk + woff + 4 * sc4);
            *(float4*)&wt[srow][64  + 4 * sc4 + 32] = *(const float4*)(Wk + woff + 4 * sc4 + 32);
            *(float4*)&wt[srow][128 + 4 * sc4]      = *(const float4*)(Wv + woff + 4 * sc4);
            *(float4*)&wt[srow][128 + 4 * sc4 + 32] = *(const float4*)(Wv + woff + 4 * sc4 + 32);
        }
        __syncthreads();

        #pragma unroll 8
        for (int kk = 0; kk < 32; ++kk) {
            float wv[12];
            *(float4*)&wv[0] = *(const float4*)&wt[kk][12 * tc];
            *(float4*)&wv[4] = *(const float4*)&wt[kk][12 * tc + 4];
            *(float4*)&wv[8] = *(const float4*)&wt[kk][12 * tc + 8];
            const float x0 = xs[2 * tr][kk];
            const float x1 = xs[2 * tr + 1][kk];
            #pragma unroll
            for (int j = 0; j < 12; ++j) {
                acc[0][j] = fmaf(x0, wv[j], acc[0][j]);
                acc[1][j] = fmaf(x1, wv[j], acc[1][j]);
            }
        }
    }

    // store (scalar; cols may straddle q/k/v)
    #pragma unroll
    for (int i = 0; i < 2; ++i) {
        const size_t row = r0 + 2 * tr + i;
        #pragma unroll
        for (int j = 0; j < 12; ++j) {
            const int c = 12 * tc + j;
            const float a = acc[i][j];
            if (c < 64)       q[row * HS + c]        = a + bq[c];
            else if (c < 128) k[row * HS + (c - 64)] = a + bk[c - 64];
            else              v[row * HS + (c - 128)] = a;
        }
    }
}

// ---------------------------------------------------------------------------
// Kernel 2: flash-style attention partial. Block = (Q-tile of 64 rows,
// j-chunk of 512). Online softmax; writes unnormalized O + (m,l) per row.
// Scale is *sqrt(hs) = *8 (faithful to reference).
// ---------------------------------------------------------------------------
__global__ __launch_bounds__(256) void attn_kernel(
    const float* __restrict__ q_ws, const float* __restrict__ k_ws,
    const float* __restrict__ v_ws, const int* __restrict__ maskp,
    float* __restrict__ part_O, float* __restrict__ part_ml)
{
    __shared__ float qs[64][68];
    __shared__ float ks[64][68];
    __shared__ float vs[64][64];
    __shared__ float ss[64][65];
    __shared__ float m_run[64], l_run[64], alpha_s[64], msafe_s[64];
    __shared__ float red[256];

    const int tile  = blockIdx.x;
    const int chunk = blockIdx.y;
    const int r0 = tile * 64;
    const int tb = r0 / T_LEN;        // batch
    const int t0 = r0 - tb * T_LEN;   // first t in tile
    const int mask = (*maskp != 0);
    const int n_max = mask ? (t0 + 64) : T_LEN;   // max valid-j count over tile
    const int j0 = chunk * JCH;
    if (j0 >= n_max) return;          // dead block (combine never reads it)
    const int hi  = min(j0 + JCH, n_max);
    const int njt = (hi - j0 + 63) >> 6;

    const int tid = threadIdx.x;
    const int g  = tid >> 4;          // row group: rows 4g..4g+3
    const int jp = tid & 15;          // phase A: j in {jp, jp+16, jp+32, jp+48}
                                      // phase B: dims 4*jp..4*jp+3

    // stage Q tile
    #pragma unroll
    for (int it = 0; it < 4; ++it) {
        const int row = (tid >> 4) + 16 * it;
        const int c4  = tid & 15;
        *(float4*)&qs[row][4 * c4] =
            *(const float4*)(q_ws + (size_t)(r0 + row) * HS + 4 * c4);
    }
    if (tid < 64) { m_run[tid] = -INFINITY; l_run[tid] = 0.f; }

    float o_acc[4][4];
    #pragma unroll
    for (int i = 0; i < 4; ++i)
        #pragma unroll
        for (int d = 0; d < 4; ++d) o_acc[i][d] = 0.f;

    __syncthreads();

    for (int jt = 0; jt < njt; ++jt) {
        const int jbase = j0 + jt * 64;
        __syncthreads();   // protect prior iteration's ks/vs/ss readers
        // stage K,V tiles
        #pragma unroll
        for (int it = 0; it < 4; ++it) {
            const int row = (tid >> 4) + 16 * it;
            const int c4  = tid & 15;
            const size_t gro = ((size_t)tb * T_LEN + jbase + row) * HS + 4 * c4;
            *(float4*)&ks[row][4 * c4] = *(const float4*)(k_ws + gro);
            *(float4*)&vs[row][4 * c4] = *(const float4*)(v_ws + gro);
        }
        __syncthreads();

        // phase A: scores s[4 rows][4 j-slots]
        float s_acc[4][4];
        #pragma unroll
        for (int i = 0; i < 4; ++i)
            #pragma unroll
            for (int jj = 0; jj < 4; ++jj) s_acc[i][jj] = 0.f;

        #pragma unroll 4
        for (int dc = 0; dc < 16; ++dc) {
            float4 q4[4], k4[4];
            #pragma unroll
            for (int i = 0; i < 4; ++i)
                q4[i] = *(const float4*)&qs[4 * g + i][4 * dc];
            #pragma unroll
            for (int jj = 0; jj < 4; ++jj)
                k4[jj] = *(const float4*)&ks[jp + 16 * jj][4 * dc];
            #pragma unroll
            for (int i = 0; i < 4; ++i)
                #pragma unroll
                for (int jj = 0; jj < 4; ++jj) {
                    s_acc[i][jj] = fmaf(q4[i].x, k4[jj].x, s_acc[i][jj]);
                    s_acc[i][jj] = fmaf(q4[i].y, k4[jj].y, s_acc[i][jj]);
                    s_acc[i][jj] = fmaf(q4[i].z, k4[jj].z, s_acc[i][jj]);
                    s_acc[i][jj] = fmaf(q4[i].w, k4[jj].w, s_acc[i][jj]);
                }
        }
        #pragma unroll
        for (int i = 0; i < 4; ++i) {
            const int t = t0 + 4 * g + i;
            const int jlim = mask ? t : (T_LEN - 1);
            #pragma unroll
            for (int jj = 0; jj < 4; ++jj) {
                const int jg = jbase + jp + 16 * jj;
                ss[4 * g + i][jp + 16 * jj] =
                    (jg <= jlim) ? 8.0f * s_acc[i][jj] : -INFINITY;
            }
        }
        __syncthreads();

        // tile max per row (4 threads/row)
        {
            const int row = tid >> 2, qq = tid & 3;
            float mx = -INFINITY;
            #pragma unroll
            for (int j = 16 * qq; j < 16 * qq + 16; ++j)
                mx = fmaxf(mx, ss[row][j]);
            red[tid] = mx;
        }
        __syncthreads();
        if (tid < 64) {
            const float mt = fmaxf(fmaxf(red[4 * tid], red[4 * tid + 1]),
                                   fmaxf(red[4 * tid + 2], red[4 * tid + 3]));
            const float mo = m_run[tid];
            const float mn = fmaxf(mo, mt);
            const float msafe = (mn == -INFINITY) ? 0.f : mn;
            alpha_s[tid] = __expf(mo - msafe);   // mo=-inf -> 0, never NaN
            msafe_s[tid] = msafe;
            m_run[tid] = mn;
        }
        __syncthreads();

        // exp in place + row partial sums
        {
            const int row = tid >> 2, qq = tid & 3;
            const float msafe = msafe_s[row];
            float ls = 0.f;
            #pragma unroll
            for (int j = 16 * qq; j < 16 * qq + 16; ++j) {
                const float e = __expf(ss[row][j] - msafe);
                ss[row][j] = e;
                ls += e;
            }
            red[tid] = ls;
        }
        __syncthreads();
        if (tid < 64)
            l_run[tid] = l_run[tid] * alpha_s[tid] +
                         red[4 * tid] + red[4 * tid + 1] +
                         red[4 * tid + 2] + red[4 * tid + 3];

        // phase B: O = O*alpha + E @ V   (thread: rows 4g..4g+3, dims 4jp..4jp+3)
        #pragma unroll
        for (int i = 0; i < 4; ++i) {
            const float a = alpha_s[4 * g + i];
            #pragma unroll
            for (int d = 0; d < 4; ++d) o_acc[i][d] *= a;
        }
        #pragma unroll 4
        for (int j = 0; j < 64; ++j) {
            const float4 v4 = *(const float4*)&vs[j][4 * jp];
            #pragma unroll
            for (int i = 0; i < 4; ++i) {
                const float e = ss[4 * g + i][j];
                o_acc[i][0] = fmaf(e, v4.x, o_acc[i][0]);
                o_acc[i][1] = fmaf(e, v4.y, o_acc[i][1]);
                o_acc[i][2] = fmaf(e, v4.z, o_acc[i][2]);
                o_acc[i][3] = fmaf(e, v4.w, o_acc[i][3]);
            }
        }
        // loop-top __syncthreads protects ss/vs before restaging
    }

    // write partials
    #pragma unroll
    for (int i = 0; i < 4; ++i) {
        float4 o;
        o.x = o_acc[i][0]; o.y = o_acc[i][1]; o.z = o_acc[i][2]; o.w = o_acc[i][3];
        *(float4*)(part_O + ((size_t)(r0 + 4 * g + i) * NCH + chunk) * HS + 4 * jp) = o;
    }
    __syncthreads();   // m_run/l_run final
    if (tid < 64) {
        float2 ml; ml.x = m_run[tid]; ml.y = l_run[tid];
        *(float2*)(part_ml + ((size_t)(r0 + tid) * NCH + chunk) * 2) = ml;
    }
}

// ---------------------------------------------------------------------------
// Kernel 3: combine chunk partials. 1 thread per (row, dim).
// ---------------------------------------------------------------------------
__global__ __launch_bounds__(256) void combine_kernel(
    const float* __restrict__ part_O, const float* __restrict__ part_ml,
    const int* __restrict__ maskp, float* __restrict__ out)
{
    const int f = blockIdx.x * 256 + threadIdx.x;
    const int row = f >> 6;
    const int d = f & 63;
    const int t = row & (T_LEN - 1);
    const int mask = (*maskp != 0);
    const int n = mask ? (t + 1) : T_LEN;
    const int nc = (n + JCH - 1) / JCH;

    float mv[NCH], lv[NCH];
    float M = -INFINITY;
    for (int c = 0; c < nc; ++c) {
        const float2 ml = *(const float2*)(part_ml + ((size_t)row * NCH + c) * 2);
        mv[c] = ml.x; lv[c] = ml.y;
        M = fmaxf(M, ml.x);
    }
    float L = 0.f, O = 0.f;
    for (int c = 0; c < nc; ++c) {
        const float w = __expf(mv[c] - M);
        L += lv[c] * w;
        O = fmaf(part_O[((size_t)row * NCH + c) * HS + d], w, O);
    }
    out[(size_t)row * HS + d] = O / L;
}

// ---------------------------------------------------------------------------
extern "C" void kernel_launch(void* const* d_in, const int* in_sizes, int n_in,
                              void* d_out, int out_size, void* d_ws, size_t ws_size,
                              hipStream_t stream) {
    const float* x  = (const float*)d_in[0];
    const float* Wq = (const float*)d_in[1];
    const float* bq = (const float*)d_in[2];
    const float* Wk = (const float*)d_in[3];
    const float* bk = (const float*)d_in[4];
    const float* Wv = (const float*)d_in[5];
    const int* maskp = (const int*)d_in[6];

    const int BT = in_sizes[0] / D_MODEL;   // 8192

    // ws layout (floats): q,k,v [BT*64 each], part_O [BT*4*64], part_ml [BT*4*2]
    float* q  = (float*)d_ws;
    float* k  = q + (size_t)BT * HS;
    float* v  = k + (size_t)BT * HS;
    float* pO = v + (size_t)BT * HS;
    float* pml = pO + (size_t)BT * NCH * HS;

    qkv_kernel<<<BT / 32, 256, 0, stream>>>(x, Wq, bq, Wk, bk, Wv, q, k, v);
    dim3 agrid(BT / 64, NCH);
    attn_kernel<<<agrid, 256, 0, stream>>>(q, k, v, maskp, pO, pml);
    combine_kernel<<<(BT * HS) / 256, 256, 0, stream>>>(pO, pml, maskp, (float*)d_out);
}

// Round 5
// 220.874 us; speedup vs baseline: 4.4726x; 1.0923x over previous
//
#include <hip/hip_runtime.h>
#include <hip/hip_bf16.h>

// AttentionHead: B=4, T=2048, C=1024, hs=64. All fp32.
#define D_MODEL 1024
#define HS 64
#define T_LEN 2048
#define JCH 512          // j-chunk width per attention block
#define NCH 4            // max chunks per row = T_LEN/JCH

// ---------------------------------------------------------------------------
// Kernel 1: QKV projection, tiled GEMM [BT x 1024] @ [1024 x 192].
// Block: 16 rows x 192 cols, 256 threads, K-chunks of 64.
// Grid 512 -> 2 blocks/CU (was 256 -> 1/CU, 11% occupancy, VALUBusy 20%).
// Thread: 1 row x 12 cols.
// ---------------------------------------------------------------------------
__global__ __launch_bounds__(256) void qkv_kernel(
    const float* __restrict__ x,
    const float* __restrict__ Wq, const float* __restrict__ bq,
    const float* __restrict__ Wk, const float* __restrict__ bk,
    const float* __restrict__ Wv,
    float* __restrict__ q, float* __restrict__ k, float* __restrict__ v)
{
    __shared__ float xs[16][68];      // 16 rows x 64 k (+pad)
    __shared__ float wt[64][196];     // 64 k x 192 cols (+pad)

    const int r0  = blockIdx.x * 16;
    const int tid = threadIdx.x;
    const int tc  = tid & 15;         // col group: cols 12*tc..12*tc+11
    const int tr  = tid >> 4;         // row 0..15

    float acc[12];
    #pragma unroll
    for (int j = 0; j < 12; ++j) acc[j] = 0.f;

    for (int k0 = 0; k0 < D_MODEL; k0 += 64) {
        __syncthreads();
        // stage x tile 16x64: one float4/thread
        {
            const int row = tid >> 4;        // 0..15
            const int c4  = tid & 15;        // 0..15
            *(float4*)&xs[row][4 * c4] =
                *(const float4*)(x + (size_t)(r0 + row) * D_MODEL + k0 + 4 * c4);
        }
        // stage W tile 64x192: 12 float4/thread, full coverage (64*48 float4)
        #pragma unroll
        for (int m = 0; m < 12; ++m) {
            const int idx  = tid + 256 * m;   // 0..3071
            const int krow = idx / 48;        // 0..63
            const int c4   = idx % 48;        // 0..47
            const float* src = (c4 < 16) ? Wq : (c4 < 32) ? Wk : Wv;
            const int cc = (c4 & 15) * 4;     // 0..60
            *(float4*)&wt[krow][(c4 >> 4) * 64 + cc] =
                *(const float4*)(src + (size_t)(k0 + krow) * HS + cc);
        }
        __syncthreads();

        #pragma unroll 4
        for (int q4i = 0; q4i < 16; ++q4i) {
            const float4 xv = *(const float4*)&xs[tr][4 * q4i];
            const float xe[4] = {xv.x, xv.y, xv.z, xv.w};
            #pragma unroll
            for (int kk = 0; kk < 4; ++kk) {
                float wv[12];
                *(float4*)&wv[0] = *(const float4*)&wt[4 * q4i + kk][12 * tc];
                *(float4*)&wv[4] = *(const float4*)&wt[4 * q4i + kk][12 * tc + 4];
                *(float4*)&wv[8] = *(const float4*)&wt[4 * q4i + kk][12 * tc + 8];
                #pragma unroll
                for (int j = 0; j < 12; ++j)
                    acc[j] = fmaf(xe[kk], wv[j], acc[j]);
            }
        }
    }

    // store (cols may straddle q/k/v)
    const size_t row = r0 + tr;
    #pragma unroll
    for (int j = 0; j < 12; ++j) {
        const int c = 12 * tc + j;
        const float a = acc[j];
        if (c < 64)       q[row * HS + c]         = a + bq[c];
        else if (c < 128) k[row * HS + (c - 64)]  = a + bk[c - 64];
        else              v[row * HS + (c - 128)] = a;
    }
}

// ---------------------------------------------------------------------------
// Kernel 2: flash-style attention partial. Block = (Q-tile of 32 rows,
// j-chunk of 512). Softmax stats in REGISTERS via 16-lane shuffle
// reductions -> 3 barriers per 64-j tile (was 6). Grid (256,4): 640 live
// causal blocks (was 320). Scale *sqrt(hs)=*8 faithful to reference.
// Thread: g=tid>>4 owns rows {2g,2g+1}; jp=tid&15.
// ---------------------------------------------------------------------------
__global__ __launch_bounds__(256) void attn_kernel(
    const float* __restrict__ q_ws, const float* __restrict__ k_ws,
    const float* __restrict__ v_ws, const int* __restrict__ maskp,
    float* __restrict__ part_O, float* __restrict__ part_ml)
{
    __shared__ float qs[32][68];
    __shared__ float ks[64][68];
    __shared__ float vs[64][64];
    __shared__ float ss[32][65];

    const int tile  = blockIdx.x;
    const int chunk = blockIdx.y;
    const int r0 = tile * 32;
    const int tb = r0 / T_LEN;        // batch
    const int t0 = r0 - tb * T_LEN;   // first t in tile
    const int mask = (*maskp != 0);
    const int n_max = mask ? (t0 + 32) : T_LEN;
    const int j0 = chunk * JCH;
    if (j0 >= n_max) return;          // dead block (combine never reads it)
    const int hi  = min(j0 + JCH, n_max);
    const int njt = (hi - j0 + 63) >> 6;

    const int tid = threadIdx.x;
    const int g  = tid >> 4;          // rows 2g, 2g+1
    const int jp = tid & 15;          // phase A: j in {jp,+16,+32,+48}; B: dims 4jp..+3

    // stage Q tile (32x64): 2 float4/thread
    #pragma unroll
    for (int it = 0; it < 2; ++it) {
        const int idx = tid + 256 * it;        // 0..511
        const int row = idx >> 4, c4 = idx & 15;
        *(float4*)&qs[row][4 * c4] =
            *(const float4*)(q_ws + (size_t)(r0 + row) * HS + 4 * c4);
    }

    float o_acc[2][4];
    #pragma unroll
    for (int i = 0; i < 2; ++i)
        #pragma unroll
        for (int d = 0; d < 4; ++d) o_acc[i][d] = 0.f;
    float m_r[2] = {-INFINITY, -INFINITY};
    float l_r[2] = {0.f, 0.f};

    for (int jt = 0; jt < njt; ++jt) {
        const int jbase = j0 + jt * 64;
        __syncthreads();   // jt=0: qs ready; jt>0: prior ks/vs/ss readers done
        // stage K,V tiles (64x64 each): 4 float4/thread/matrix
        #pragma unroll
        for (int it = 0; it < 4; ++it) {
            const int idx = tid + 256 * it;    // 0..1023
            const int row = idx >> 4, c4 = idx & 15;
            const size_t gro = ((size_t)tb * T_LEN + jbase + row) * HS + 4 * c4;
            *(float4*)&ks[row][4 * c4] = *(const float4*)(k_ws + gro);
            *(float4*)&vs[row][4 * c4] = *(const float4*)(v_ws + gro);
        }
        __syncthreads();

        // phase A: scores s[2 rows][4 j-slots]
        float s_acc[2][4];
        #pragma unroll
        for (int i = 0; i < 2; ++i)
            #pragma unroll
            for (int jj = 0; jj < 4; ++jj) s_acc[i][jj] = 0.f;

        #pragma unroll 4
        for (int dc = 0; dc < 16; ++dc) {
            float4 q4[2], k4[4];
            #pragma unroll
            for (int i = 0; i < 2; ++i)
                q4[i] = *(const float4*)&qs[2 * g + i][4 * dc];
            #pragma unroll
            for (int jj = 0; jj < 4; ++jj)
                k4[jj] = *(const float4*)&ks[jp + 16 * jj][4 * dc];
            #pragma unroll
            for (int i = 0; i < 2; ++i)
                #pragma unroll
                for (int jj = 0; jj < 4; ++jj) {
                    s_acc[i][jj] = fmaf(q4[i].x, k4[jj].x, s_acc[i][jj]);
                    s_acc[i][jj] = fmaf(q4[i].y, k4[jj].y, s_acc[i][jj]);
                    s_acc[i][jj] = fmaf(q4[i].z, k4[jj].z, s_acc[i][jj]);
                    s_acc[i][jj] = fmaf(q4[i].w, k4[jj].w, s_acc[i][jj]);
                }
        }

        // mask + scale; per-thread row maxes
        float sv[2][4], rmax[2];
        #pragma unroll
        for (int i = 0; i < 2; ++i) {
            const int t = t0 + 2 * g + i;
            const int jlim = mask ? t : (T_LEN - 1);
            #pragma unroll
            for (int jj = 0; jj < 4; ++jj) {
                const int jg = jbase + jp + 16 * jj;
                sv[i][jj] = (jg <= jlim) ? 8.0f * s_acc[i][jj] : -INFINITY;
            }
            rmax[i] = fmaxf(fmaxf(sv[i][0], sv[i][1]), fmaxf(sv[i][2], sv[i][3]));
        }
        // 16-lane shuffle max (lanes sharing g are consecutive: xor 1,2,4,8)
        #pragma unroll
        for (int d = 1; d < 16; d <<= 1) {
            #pragma unroll
            for (int i = 0; i < 2; ++i)
                rmax[i] = fmaxf(rmax[i], __shfl_xor(rmax[i], d));
        }
        // online-softmax update (all 16 lanes of the group compute identically)
        float alpha[2], msafe[2];
        #pragma unroll
        for (int i = 0; i < 2; ++i) {
            const float mn = fmaxf(m_r[i], rmax[i]);
            msafe[i] = (mn == -INFINITY) ? 0.f : mn;
            alpha[i] = __expf(m_r[i] - msafe[i]);   // -inf -> 0, never NaN
            m_r[i] = mn;
        }
        // exp + write ss + row partial sums
        float rsum[2];
        #pragma unroll
        for (int i = 0; i < 2; ++i) {
            float s0 = 0.f;
            #pragma unroll
            for (int jj = 0; jj < 4; ++jj) {
                const float e = __expf(sv[i][jj] - msafe[i]);
                ss[2 * g + i][jp + 16 * jj] = e;
                s0 += e;
            }
            rsum[i] = s0;
        }
        #pragma unroll
        for (int d = 1; d < 16; d <<= 1) {
            #pragma unroll
            for (int i = 0; i < 2; ++i)
                rsum[i] += __shfl_xor(rsum[i], d);
        }
        #pragma unroll
        for (int i = 0; i < 2; ++i)
            l_r[i] = l_r[i] * alpha[i] + rsum[i];

        __syncthreads();   // ss ready for phase B

        // phase B: O = O*alpha + E @ V  (rows 2g..2g+1, dims 4jp..4jp+3)
        #pragma unroll
        for (int i = 0; i < 2; ++i)
            #pragma unroll
            for (int d = 0; d < 4; ++d) o_acc[i][d] *= alpha[i];
        #pragma unroll 4
        for (int j = 0; j < 64; ++j) {
            const float4 v4 = *(const float4*)&vs[j][4 * jp];
            #pragma unroll
            for (int i = 0; i < 2; ++i) {
                const float e = ss[2 * g + i][j];
                o_acc[i][0] = fmaf(e, v4.x, o_acc[i][0]);
                o_acc[i][1] = fmaf(e, v4.y, o_acc[i][1]);
                o_acc[i][2] = fmaf(e, v4.z, o_acc[i][2]);
                o_acc[i][3] = fmaf(e, v4.w, o_acc[i][3]);
            }
        }
    }

    // write partials (stats live in registers; lane jp==0 owns the ml write)
    #pragma unroll
    for (int i = 0; i < 2; ++i) {
        float4 o;
        o.x = o_acc[i][0]; o.y = o_acc[i][1]; o.z = o_acc[i][2]; o.w = o_acc[i][3];
        *(float4*)(part_O + ((size_t)(r0 + 2 * g + i) * NCH + chunk) * HS + 4 * jp) = o;
    }
    if (jp == 0) {
        #pragma unroll
        for (int i = 0; i < 2; ++i) {
            float2 ml; ml.x = m_r[i]; ml.y = l_r[i];
            *(float2*)(part_ml + ((size_t)(r0 + 2 * g + i) * NCH + chunk) * 2) = ml;
        }
    }
}

// ---------------------------------------------------------------------------
// Kernel 3: combine chunk partials. 1 thread per (row, dim).
// ---------------------------------------------------------------------------
__global__ __launch_bounds__(256) void combine_kernel(
    const float* __restrict__ part_O, const float* __restrict__ part_ml,
    const int* __restrict__ maskp, float* __restrict__ out)
{
    const int f = blockIdx.x * 256 + threadIdx.x;
    const int row = f >> 6;
    const int d = f & 63;
    const int t = row & (T_LEN - 1);
    const int mask = (*maskp != 0);
    const int n = mask ? (t + 1) : T_LEN;
    const int nc = (n + JCH - 1) / JCH;

    float mv[NCH], lv[NCH];
    float M = -INFINITY;
    for (int c = 0; c < nc; ++c) {
        const float2 ml = *(const float2*)(part_ml + ((size_t)row * NCH + c) * 2);
        mv[c] = ml.x; lv[c] = ml.y;
        M = fmaxf(M, ml.x);
    }
    float L = 0.f, O = 0.f;
    for (int c = 0; c < nc; ++c) {
        const float w = __expf(mv[c] - M);
        L += lv[c] * w;
        O = fmaf(part_O[((size_t)row * NCH + c) * HS + d], w, O);
    }
    out[(size_t)row * HS + d] = O / L;
}

// ---------------------------------------------------------------------------
extern "C" void kernel_launch(void* const* d_in, const int* in_sizes, int n_in,
                              void* d_out, int out_size, void* d_ws, size_t ws_size,
                              hipStream_t stream) {
    const float* x  = (const float*)d_in[0];
    const float* Wq = (const float*)d_in[1];
    const float* bq = (const float*)d_in[2];
    const float* Wk = (const float*)d_in[3];
    const float* bk = (const float*)d_in[4];
    const float* Wv = (const float*)d_in[5];
    const int* maskp = (const int*)d_in[6];

    const int BT = in_sizes[0] / D_MODEL;   // 8192

    // ws layout (floats): q,k,v [BT*64 each], part_O [BT*4*64], part_ml [BT*4*2]
    float* q  = (float*)d_ws;
    float* k  = q + (size_t)BT * HS;
    float* v  = k + (size_t)BT * HS;
    float* pO = v + (size_t)BT * HS;
    float* pml = pO + (size_t)BT * NCH * HS;

    qkv_kernel<<<BT / 16, 256, 0, stream>>>(x, Wq, bq, Wk, bk, Wv, q, k, v);
    dim3 agrid(BT / 32, NCH);
    attn_kernel<<<agrid, 256, 0, stream>>>(q, k, v, maskp, pO, pml);
    combine_kernel<<<(BT * HS) / 256, 256, 0, stream>>>(pO, pml, maskp, (float*)d_out);
}

// Round 6
// 204.700 us; speedup vs baseline: 4.8260x; 1.0790x over previous
//
#include <hip/hip_runtime.h>
#include <hip/hip_bf16.h>

// AttentionHead: B=4, T=2048, C=1024, hs=64. All fp32 in/out.
#define D_MODEL 1024
#define HS 64
#define T_LEN 2048
#define JCH 512          // j-chunk width per attention block
#define NCH 4            // max chunks per row = T_LEN/JCH

typedef __attribute__((ext_vector_type(8))) short bf16x8;   // MFMA A/B frag
typedef __attribute__((ext_vector_type(4))) float f32x4;    // MFMA C/D frag

// ---------------------------------------------------------------------------
// Kernel 0: W prep — split fp32 W into bf16 hi/lo (truncation split) and
// transpose to [n][k] so B-fragments load as contiguous 16B.
// n in 0..191: 0..63=Wq, 64..127=Wk, 128..191=Wv.
// ---------------------------------------------------------------------------
__global__ __launch_bounds__(256) void wprep_kernel(
    const float* __restrict__ Wq, const float* __restrict__ Wk,
    const float* __restrict__ Wv, short* __restrict__ Wh, short* __restrict__ Wl)
{
    const int idx = blockIdx.x * 256 + threadIdx.x;   // 0 .. 192*1024-1
    const int k = idx / 192;
    const int n = idx - k * 192;
    const float* W = (n < 64) ? Wq : (n < 128) ? Wk : Wv;
    const float val = W[k * HS + (n & 63)];
    const unsigned int b = __float_as_uint(val);
    const unsigned short h = (unsigned short)(b >> 16);
    const float r = val - __uint_as_float((unsigned int)h << 16);
    const unsigned short l = (unsigned short)(__float_as_uint(r) >> 16);
    Wh[(size_t)n * D_MODEL + k] = (short)h;
    Wl[(size_t)n * D_MODEL + k] = (short)l;
}

// ---------------------------------------------------------------------------
// Kernel 1: QKV projection via split-bf16 MFMA.
// C = [8192 x 192] = x[8192x1024] @ Wcat[1024x192], fp32-accurate via
// xh*wh + xh*wl + xl*wh (3 MFMA passes, 16x16x32 bf16).
// Block: 64 M x 192 N, 4 waves; wave owns 4 Mtiles x 3 Ntiles (48 f32 acc).
// LDS holds fragments in lane-linear order -> conflict-free b128 reads.
// ---------------------------------------------------------------------------
__global__ __launch_bounds__(256) void qkv_kernel(
    const float* __restrict__ x,
    const short* __restrict__ Wh, const short* __restrict__ Wl,
    const float* __restrict__ bq, const float* __restrict__ bk,
    float* __restrict__ q, float* __restrict__ k, float* __restrict__ v)
{
    // per-tile stride 520 shorts = 1040 B (16B-aligned, breaks bank periodicity)
    __shared__ short Ah[4 * 520], Al[4 * 520];
    __shared__ short Bh[12 * 520], Bl[12 * 520];

    const int tid  = threadIdx.x;
    const int r0   = blockIdx.x * 64;
    const int wave = tid >> 6;
    const int lane = tid & 63;
    const int wn0  = wave * 3;          // first ntile owned by this wave

    f32x4 acc[4][3];
    #pragma unroll
    for (int mt = 0; mt < 4; ++mt)
        #pragma unroll
        for (int j = 0; j < 3; ++j) acc[mt][j] = (f32x4)(0.f);

    const int sm  = tid & 63;           // staging: A row
    const int skc = tid >> 6;           // staging: k-chunk (8 k each)

    for (int k0 = 0; k0 < D_MODEL; k0 += 32) {
        __syncthreads();
        // ---- stage A: x[r0+sm][k0+skc*8 ..+7] -> hi/lo bf16 frag slots
        {
            const float* src = x + (size_t)(r0 + sm) * D_MODEL + k0 + skc * 8;
            float xv[8];
            *(float4*)&xv[0] = *(const float4*)src;
            *(float4*)&xv[4] = *(const float4*)(src + 4);
            union { unsigned short u[8]; int4 v; } uh, ul;
            #pragma unroll
            for (int i = 0; i < 8; ++i) {
                const unsigned int b = __float_as_uint(xv[i]);
                const unsigned short h = (unsigned short)(b >> 16);
                const float r = xv[i] - __uint_as_float((unsigned int)h << 16);
                uh.u[i] = h;
                ul.u[i] = (unsigned short)(__float_as_uint(r) >> 16);
            }
            const int mt   = sm >> 4;
            const int slot = (skc << 4) | (sm & 15);
            *(int4*)&Ah[mt * 520 + slot * 8] = uh.v;
            *(int4*)&Al[mt * 520 + slot * 8] = ul.v;
        }
        // ---- stage B: pre-split W^T -> frag slots (16B contiguous copies)
        #pragma unroll
        for (int i = 0; i < 3; ++i) {
            const int s   = tid + 256 * i;     // 0..767
            const int nt  = s >> 6;
            const int sl  = s & 63;
            const int kc  = sl >> 4;
            const int nn  = sl & 15;
            const size_t off = (size_t)(nt * 16 + nn) * D_MODEL + k0 + kc * 8;
            *(int4*)&Bh[nt * 520 + sl * 8] = *(const int4*)(Wh + off);
            *(int4*)&Bl[nt * 520 + sl * 8] = *(const int4*)(Wl + off);
        }
        __syncthreads();

        // ---- MFMA: 4 Mtiles x 3 Ntiles x 3 split-passes
        bf16x8 afh[4], afl[4];
        #pragma unroll
        for (int mt = 0; mt < 4; ++mt) {
            afh[mt] = *(const bf16x8*)&Ah[mt * 520 + lane * 8];
            afl[mt] = *(const bf16x8*)&Al[mt * 520 + lane * 8];
        }
        #pragma unroll
        for (int j = 0; j < 3; ++j) {
            const int nt = wn0 + j;
            const bf16x8 bfh = *(const bf16x8*)&Bh[nt * 520 + lane * 8];
            const bf16x8 bfl = *(const bf16x8*)&Bl[nt * 520 + lane * 8];
            #pragma unroll
            for (int mt = 0; mt < 4; ++mt) {
                acc[mt][j] = __builtin_amdgcn_mfma_f32_16x16x32_bf16(afh[mt], bfh, acc[mt][j], 0, 0, 0);
                acc[mt][j] = __builtin_amdgcn_mfma_f32_16x16x32_bf16(afh[mt], bfl, acc[mt][j], 0, 0, 0);
                acc[mt][j] = __builtin_amdgcn_mfma_f32_16x16x32_bf16(afl[mt], bfh, acc[mt][j], 0, 0, 0);
            }
        }
    }

    // ---- epilogue: C/D layout col=lane&15, row=(lane>>4)*4+reg
    #pragma unroll
    for (int j = 0; j < 3; ++j) {
        const int c = (wn0 + j) * 16 + (lane & 15);
        const float bias = (c < 64) ? bq[c] : (c < 128) ? bk[c - 64] : 0.f;
        float* dst = (c < 64) ? (q + c) : (c < 128) ? (k + c - 64) : (v + c - 128);
        #pragma unroll
        for (int mt = 0; mt < 4; ++mt) {
            const int rowb = r0 + mt * 16 + (lane >> 4) * 4;
            #pragma unroll
            for (int r = 0; r < 4; ++r)
                dst[(size_t)(rowb + r) * HS] = acc[mt][j][r] + bias;
        }
    }
}

// ---------------------------------------------------------------------------
// Kernel 2: flash-style attention partial (UNCHANGED from round 5 — passing).
// ---------------------------------------------------------------------------
__global__ __launch_bounds__(256) void attn_kernel(
    const float* __restrict__ q_ws, const float* __restrict__ k_ws,
    const float* __restrict__ v_ws, const int* __restrict__ maskp,
    float* __restrict__ part_O, float* __restrict__ part_ml)
{
    __shared__ float qs[32][68];
    __shared__ float ks[64][68];
    __shared__ float vs[64][64];
    __shared__ float ss[32][65];

    const int tile  = blockIdx.x;
    const int chunk = blockIdx.y;
    const int r0 = tile * 32;
    const int tb = r0 / T_LEN;
    const int t0 = r0 - tb * T_LEN;
    const int mask = (*maskp != 0);
    const int n_max = mask ? (t0 + 32) : T_LEN;
    const int j0 = chunk * JCH;
    if (j0 >= n_max) return;
    const int hi  = min(j0 + JCH, n_max);
    const int njt = (hi - j0 + 63) >> 6;

    const int tid = threadIdx.x;
    const int g  = tid >> 4;
    const int jp = tid & 15;

    #pragma unroll
    for (int it = 0; it < 2; ++it) {
        const int idx = tid + 256 * it;
        const int row = idx >> 4, c4 = idx & 15;
        *(float4*)&qs[row][4 * c4] =
            *(const float4*)(q_ws + (size_t)(r0 + row) * HS + 4 * c4);
    }

    float o_acc[2][4];
    #pragma unroll
    for (int i = 0; i < 2; ++i)
        #pragma unroll
        for (int d = 0; d < 4; ++d) o_acc[i][d] = 0.f;
    float m_r[2] = {-INFINITY, -INFINITY};
    float l_r[2] = {0.f, 0.f};

    for (int jt = 0; jt < njt; ++jt) {
        const int jbase = j0 + jt * 64;
        __syncthreads();
        #pragma unroll
        for (int it = 0; it < 4; ++it) {
            const int idx = tid + 256 * it;
            const int row = idx >> 4, c4 = idx & 15;
            const size_t gro = ((size_t)tb * T_LEN + jbase + row) * HS + 4 * c4;
            *(float4*)&ks[row][4 * c4] = *(const float4*)(k_ws + gro);
            *(float4*)&vs[row][4 * c4] = *(const float4*)(v_ws + gro);
        }
        __syncthreads();

        float s_acc[2][4];
        #pragma unroll
        for (int i = 0; i < 2; ++i)
            #pragma unroll
            for (int jj = 0; jj < 4; ++jj) s_acc[i][jj] = 0.f;

        #pragma unroll 4
        for (int dc = 0; dc < 16; ++dc) {
            float4 q4[2], k4[4];
            #pragma unroll
            for (int i = 0; i < 2; ++i)
                q4[i] = *(const float4*)&qs[2 * g + i][4 * dc];
            #pragma unroll
            for (int jj = 0; jj < 4; ++jj)
                k4[jj] = *(const float4*)&ks[jp + 16 * jj][4 * dc];
            #pragma unroll
            for (int i = 0; i < 2; ++i)
                #pragma unroll
                for (int jj = 0; jj < 4; ++jj) {
                    s_acc[i][jj] = fmaf(q4[i].x, k4[jj].x, s_acc[i][jj]);
                    s_acc[i][jj] = fmaf(q4[i].y, k4[jj].y, s_acc[i][jj]);
                    s_acc[i][jj] = fmaf(q4[i].z, k4[jj].z, s_acc[i][jj]);
                    s_acc[i][jj] = fmaf(q4[i].w, k4[jj].w, s_acc[i][jj]);
                }
        }

        float sv[2][4], rmax[2];
        #pragma unroll
        for (int i = 0; i < 2; ++i) {
            const int t = t0 + 2 * g + i;
            const int jlim = mask ? t : (T_LEN - 1);
            #pragma unroll
            for (int jj = 0; jj < 4; ++jj) {
                const int jg = jbase + jp + 16 * jj;
                sv[i][jj] = (jg <= jlim) ? 8.0f * s_acc[i][jj] : -INFINITY;
            }
            rmax[i] = fmaxf(fmaxf(sv[i][0], sv[i][1]), fmaxf(sv[i][2], sv[i][3]));
        }
        #pragma unroll
        for (int d = 1; d < 16; d <<= 1) {
            #pragma unroll
            for (int i = 0; i < 2; ++i)
                rmax[i] = fmaxf(rmax[i], __shfl_xor(rmax[i], d));
        }
        float alpha[2], msafe[2];
        #pragma unroll
        for (int i = 0; i < 2; ++i) {
            const float mn = fmaxf(m_r[i], rmax[i]);
            msafe[i] = (mn == -INFINITY) ? 0.f : mn;
            alpha[i] = __expf(m_r[i] - msafe[i]);
            m_r[i] = mn;
        }
        float rsum[2];
        #pragma unroll
        for (int i = 0; i < 2; ++i) {
            float s0 = 0.f;
            #pragma unroll
            for (int jj = 0; jj < 4; ++jj) {
                const float e = __expf(sv[i][jj] - msafe[i]);
                ss[2 * g + i][jp + 16 * jj] = e;
                s0 += e;
            }
            rsum[i] = s0;
        }
        #pragma unroll
        for (int d = 1; d < 16; d <<= 1) {
            #pragma unroll
            for (int i = 0; i < 2; ++i)
                rsum[i] += __shfl_xor(rsum[i], d);
        }
        #pragma unroll
        for (int i = 0; i < 2; ++i)
            l_r[i] = l_r[i] * alpha[i] + rsum[i];

        __syncthreads();

        #pragma unroll
        for (int i = 0; i < 2; ++i)
            #pragma unroll
            for (int d = 0; d < 4; ++d) o_acc[i][d] *= alpha[i];
        #pragma unroll 4
        for (int j = 0; j < 64; ++j) {
            const float4 v4 = *(const float4*)&vs[j][4 * jp];
            #pragma unroll
            for (int i = 0; i < 2; ++i) {
                const float e = ss[2 * g + i][j];
                o_acc[i][0] = fmaf(e, v4.x, o_acc[i][0]);
                o_acc[i][1] = fmaf(e, v4.y, o_acc[i][1]);
                o_acc[i][2] = fmaf(e, v4.z, o_acc[i][2]);
                o_acc[i][3] = fmaf(e, v4.w, o_acc[i][3]);
            }
        }
    }

    #pragma unroll
    for (int i = 0; i < 2; ++i) {
        float4 o;
        o.x = o_acc[i][0]; o.y = o_acc[i][1]; o.z = o_acc[i][2]; o.w = o_acc[i][3];
        *(float4*)(part_O + ((size_t)(r0 + 2 * g + i) * NCH + chunk) * HS + 4 * jp) = o;
    }
    if (jp == 0) {
        #pragma unroll
        for (int i = 0; i < 2; ++i) {
            float2 ml; ml.x = m_r[i]; ml.y = l_r[i];
            *(float2*)(part_ml + ((size_t)(r0 + 2 * g + i) * NCH + chunk) * 2) = ml;
        }
    }
}

// ---------------------------------------------------------------------------
// Kernel 3: combine chunk partials (UNCHANGED from round 5 — passing).
// ---------------------------------------------------------------------------
__global__ __launch_bounds__(256) void combine_kernel(
    const float* __restrict__ part_O, const float* __restrict__ part_ml,
    const int* __restrict__ maskp, float* __restrict__ out)
{
    const int f = blockIdx.x * 256 + threadIdx.x;
    const int row = f >> 6;
    const int d = f & 63;
    const int t = row & (T_LEN - 1);
    const int mask = (*maskp != 0);
    const int n = mask ? (t + 1) : T_LEN;
    const int nc = (n + JCH - 1) / JCH;

    float mv[NCH], lv[NCH];
    float M = -INFINITY;
    for (int c = 0; c < nc; ++c) {
        const float2 ml = *(const float2*)(part_ml + ((size_t)row * NCH + c) * 2);
        mv[c] = ml.x; lv[c] = ml.y;
        M = fmaxf(M, ml.x);
    }
    float L = 0.f, O = 0.f;
    for (int c = 0; c < nc; ++c) {
        const float w = __expf(mv[c] - M);
        L += lv[c] * w;
        O = fmaf(part_O[((size_t)row * NCH + c) * HS + d], w, O);
    }
    out[(size_t)row * HS + d] = O / L;
}

// ---------------------------------------------------------------------------
extern "C" void kernel_launch(void* const* d_in, const int* in_sizes, int n_in,
                              void* d_out, int out_size, void* d_ws, size_t ws_size,
                              hipStream_t stream) {
    const float* x  = (const float*)d_in[0];
    const float* Wq = (const float*)d_in[1];
    const float* bq = (const float*)d_in[2];
    const float* Wk = (const float*)d_in[3];
    const float* bk = (const float*)d_in[4];
    const float* Wv = (const float*)d_in[5];
    const int* maskp = (const int*)d_in[6];

    const int BT = in_sizes[0] / D_MODEL;   // 8192

    // ws layout (floats): q,k,v [BT*64 each], part_O [BT*4*64], part_ml [BT*4*2]
    float* q   = (float*)d_ws;
    float* k   = q + (size_t)BT * HS;
    float* v   = k + (size_t)BT * HS;
    float* pO  = v + (size_t)BT * HS;
    float* pml = pO + (size_t)BT * NCH * HS;

    // W split buffers ALIAS part_O: only live during wprep+qkv, and part_O is
    // first written by attn_kernel which runs strictly after qkv on this stream.
    short* Wh = (short*)pO;
    short* Wl = Wh + (size_t)192 * D_MODEL;

    wprep_kernel<<<(192 * D_MODEL) / 256, 256, 0, stream>>>(Wq, Wk, Wv, Wh, Wl);
    qkv_kernel<<<BT / 64, 256, 0, stream>>>(x, Wh, Wl, bq, bk, q, k, v);
    dim3 agrid(BT / 32, NCH);
    attn_kernel<<<agrid, 256, 0, stream>>>(q, k, v, maskp, pO, pml);
    combine_kernel<<<(BT * HS) / 256, 256, 0, stream>>>(pO, pml, maskp, (float*)d_out);
}

// Round 7
// 170.963 us; speedup vs baseline: 5.7784x; 1.1973x over previous
//
#include <hip/hip_runtime.h>
#include <hip/hip_bf16.h>

// AttentionHead: B=4, T=2048, C=1024, hs=64. All fp32 in/out.
#define D_MODEL 1024
#define HS 64
#define T_LEN 2048
#define JCH 512          // j-chunk width per attention block
#define NCH 4            // max chunks per row = T_LEN/JCH

typedef __attribute__((ext_vector_type(8))) short bf16x8;   // MFMA A/B frag
typedef __attribute__((ext_vector_type(4))) float f32x4;    // MFMA C/D frag

// split 8 floats into hi/lo bf16 (truncation split: residual exact)
__device__ inline void split8(const float* v, int4& hi, int4& lo) {
    union { unsigned short u[8]; int4 v4; } uh, ul;
    #pragma unroll
    for (int i = 0; i < 8; ++i) {
        const unsigned int b = __float_as_uint(v[i]);
        const unsigned short h = (unsigned short)(b >> 16);
        const float r = v[i] - __uint_as_float((unsigned int)h << 16);
        uh.u[i] = h;
        ul.u[i] = (unsigned short)(__float_as_uint(r) >> 16);
    }
    hi = uh.v4; lo = ul.v4;
}

// fp32 -> bf16 round-to-nearest-even (finite inputs only here)
__device__ inline unsigned short f2bf_rne(float f) {
    const unsigned int b = __float_as_uint(f);
    return (unsigned short)((b + 0x7FFFu + ((b >> 16) & 1u)) >> 16);
}
__device__ inline float bf2f(unsigned short h) {
    return __uint_as_float((unsigned int)h << 16);
}

// ---------------------------------------------------------------------------
// Kernel 0: W prep (coalesced). Block = one 64k x 64n tile of one matrix.
// Read coalesced float4 -> LDS -> write transposed split-bf16 Wh/Wl [n][k]
// with 16B vector stores. Grid = 16 k-blocks x 3 matrices = 48 blocks.
// ---------------------------------------------------------------------------
__global__ __launch_bounds__(256) void wprep_kernel(
    const float* __restrict__ Wq, const float* __restrict__ Wk,
    const float* __restrict__ Wv, short* __restrict__ Wh, short* __restrict__ Wl)
{
    __shared__ float tile[64][69];
    const int tid = threadIdx.x;
    const int kb = blockIdx.x & 15;       // k-block 0..15
    const int m  = blockIdx.x >> 4;       // matrix 0..2
    const float* W = (m == 0) ? Wq : (m == 1) ? Wk : Wv;
    #pragma unroll
    for (int it = 0; it < 4; ++it) {
        const int idx = tid + 256 * it;
        const int kr = idx >> 4, c4 = idx & 15;
        *(float4*)&tile[kr][4 * c4] =
            *(const float4*)(W + (size_t)(kb * 64 + kr) * HS + 4 * c4);
    }
    __syncthreads();
    #pragma unroll
    for (int it = 0; it < 2; ++it) {
        const int s = tid + 256 * it;     // 0..511
        const int n = s >> 3, kc = s & 7;
        float v[8];
        #pragma unroll
        for (int i = 0; i < 8; ++i) v[i] = tile[kc * 8 + i][n];
        int4 hi, lo;
        split8(v, hi, lo);
        const size_t off = (size_t)(m * 64 + n) * D_MODEL + kb * 64 + kc * 8;
        *(int4*)(Wh + off) = hi;
        *(int4*)(Wl + off) = lo;
    }
}

// ---------------------------------------------------------------------------
// Kernel 1: QKV projection via split-bf16 MFMA (structure = round 6, passing).
// Change: v is stored TRANSPOSED (vt[64][BT]) with float4 stores, so the
// attention kernel can stage V B-fragments as contiguous 16B reads.
// ---------------------------------------------------------------------------
__global__ __launch_bounds__(256) void qkv_kernel(
    const float* __restrict__ x,
    const short* __restrict__ Wh, const short* __restrict__ Wl,
    const float* __restrict__ bq, const float* __restrict__ bk,
    float* __restrict__ q, float* __restrict__ k, float* __restrict__ vt, int BT)
{
    __shared__ __align__(16) short Ah[4 * 520], Al[4 * 520];
    __shared__ __align__(16) short Bh[12 * 520], Bl[12 * 520];

    const int tid  = threadIdx.x;
    const int r0   = blockIdx.x * 64;
    const int wave = tid >> 6;
    const int lane = tid & 63;
    const int wn0  = wave * 3;

    f32x4 acc[4][3];
    #pragma unroll
    for (int mt = 0; mt < 4; ++mt)
        #pragma unroll
        for (int j = 0; j < 3; ++j) acc[mt][j] = (f32x4)(0.f);

    const int sm  = tid & 63;
    const int skc = tid >> 6;

    for (int k0 = 0; k0 < D_MODEL; k0 += 32) {
        __syncthreads();
        // stage A: x rows -> split bf16 frag slots
        {
            const float* src = x + (size_t)(r0 + sm) * D_MODEL + k0 + skc * 8;
            float xv[8];
            *(float4*)&xv[0] = *(const float4*)src;
            *(float4*)&xv[4] = *(const float4*)(src + 4);
            int4 hi, lo;
            split8(xv, hi, lo);
            const int mt   = sm >> 4;
            const int slot = (skc << 4) | (sm & 15);
            *(int4*)&Ah[mt * 520 + slot * 8] = hi;
            *(int4*)&Al[mt * 520 + slot * 8] = lo;
        }
        // stage B: pre-split W^T frag slots (16B contiguous copies)
        #pragma unroll
        for (int i = 0; i < 3; ++i) {
            const int s   = tid + 256 * i;     // 0..767
            const int nt  = s >> 6;
            const int sl  = s & 63;
            const int kc  = sl >> 4;
            const int nn  = sl & 15;
            const size_t off = (size_t)(nt * 16 + nn) * D_MODEL + k0 + kc * 8;
            *(int4*)&Bh[nt * 520 + sl * 8] = *(const int4*)(Wh + off);
            *(int4*)&Bl[nt * 520 + sl * 8] = *(const int4*)(Wl + off);
        }
        __syncthreads();

        bf16x8 afh[4], afl[4];
        #pragma unroll
        for (int mt = 0; mt < 4; ++mt) {
            afh[mt] = *(const bf16x8*)&Ah[mt * 520 + lane * 8];
            afl[mt] = *(const bf16x8*)&Al[mt * 520 + lane * 8];
        }
        #pragma unroll
        for (int j = 0; j < 3; ++j) {
            const int nt = wn0 + j;
            const bf16x8 bfh = *(const bf16x8*)&Bh[nt * 520 + lane * 8];
            const bf16x8 bfl = *(const bf16x8*)&Bl[nt * 520 + lane * 8];
            #pragma unroll
            for (int mt = 0; mt < 4; ++mt) {
                acc[mt][j] = __builtin_amdgcn_mfma_f32_16x16x32_bf16(afh[mt], bfh, acc[mt][j], 0, 0, 0);
                acc[mt][j] = __builtin_amdgcn_mfma_f32_16x16x32_bf16(afh[mt], bfl, acc[mt][j], 0, 0, 0);
                acc[mt][j] = __builtin_amdgcn_mfma_f32_16x16x32_bf16(afl[mt], bfh, acc[mt][j], 0, 0, 0);
            }
        }
    }

    // epilogue: C/D layout col=lane&15, row=(lane>>4)*4+reg
    #pragma unroll
    for (int j = 0; j < 3; ++j) {
        const int c = (wn0 + j) * 16 + (lane & 15);
        #pragma unroll
        for (int mt = 0; mt < 4; ++mt) {
            const int rowb = r0 + mt * 16 + (lane >> 4) * 4;
            if (c < 64) {
                const float bias = bq[c];
                #pragma unroll
                for (int r = 0; r < 4; ++r)
                    q[(size_t)(rowb + r) * HS + c] = acc[mt][j][r] + bias;
            } else if (c < 128) {
                const float bias = bk[c - 64];
                #pragma unroll
                for (int r = 0; r < 4; ++r)
                    k[(size_t)(rowb + r) * HS + (c - 64)] = acc[mt][j][r] + bias;
            } else {
                float4 o;
                o.x = acc[mt][j][0]; o.y = acc[mt][j][1];
                o.z = acc[mt][j][2]; o.w = acc[mt][j][3];
                *(float4*)(vt + (size_t)(c - 128) * BT + rowb) = o;
            }
        }
    }
}

// ---------------------------------------------------------------------------
// Kernel 2: flash-style attention via MFMA.
// Block = 64 q-rows x 512 j-chunk, 4 waves; wave owns 16 q-rows (no
// cross-wave softmax). QK^T: 3-pass split-bf16 (fp32-grade scores).
// P, V: single RNE-bf16. P converts C-layout -> A-layout via wave-private
// LDS (no barrier). 2 barriers per 64-j tile. Scale *8 faithful to ref.
// ---------------------------------------------------------------------------
__global__ __launch_bounds__(256) void attn_kernel(
    const float* __restrict__ q_ws, const float* __restrict__ k_ws,
    const float* __restrict__ vt_ws, const int* __restrict__ maskp,
    float* __restrict__ part_O, float* __restrict__ part_ml, int BT)
{
    // K fragments (split): slot = (jsub*2+kc)*64 + lane, 8 shorts each
    __shared__ __align__(16) short Kh[4096], Kl[4096];
    // V^T fragments (bf16): slot = (jc*4+nt)*64 + lane
    __shared__ __align__(16) short Vt[4096];
    // P per wave: [row 0..15][72 shorts] (stride 72 -> 16B-aligned rows)
    __shared__ __align__(16) short Pl[4][16 * 72];

    const int tile  = blockIdx.x;
    const int chunk = blockIdx.y;
    const int r0 = tile * 64;
    const int tb = r0 / T_LEN;
    const int t0 = r0 - tb * T_LEN;
    const int mask = (*maskp != 0);
    const int n_max = mask ? (t0 + 64) : T_LEN;
    const int j0 = chunk * JCH;
    if (j0 >= n_max) return;            // dead block (combine never reads it)
    const int hi_j = min(j0 + JCH, n_max);
    const int njt = (hi_j - j0 + 63) >> 6;   // all tiles full (64-multiples)

    const int tid  = threadIdx.x;
    const int w    = tid >> 6;
    const int lane = tid & 63;
    const int quad = lane >> 4;
    const int l15  = lane & 15;
    const int rw0  = t0 + 16 * w;            // wave's first global t
    const int rowa = r0 + 16 * w + quad * 4; // abs row base for C-layout (+r)

    // Q fragments direct from global (loop-invariant), split bf16
    bf16x8 qfh[2], qfl[2];
    {
        const float* qrow = q_ws + (size_t)(r0 + 16 * w + l15) * HS + quad * 8;
        #pragma unroll
        for (int kc = 0; kc < 2; ++kc) {
            float v[8];
            *(float4*)&v[0] = *(const float4*)(qrow + kc * 32);
            *(float4*)&v[4] = *(const float4*)(qrow + kc * 32 + 4);
            union { int4 i; bf16x8 b; } ch, cl;
            split8(v, ch.i, cl.i);
            qfh[kc] = ch.b;
            qfl[kc] = cl.b;
        }
    }

    f32x4 oacc[4];
    #pragma unroll
    for (int nt = 0; nt < 4; ++nt) oacc[nt] = (f32x4)(0.f);
    float m_r[4] = {-INFINITY, -INFINITY, -INFINITY, -INFINITY};
    float l_r[4] = {0.f, 0.f, 0.f, 0.f};

    const float* kbase = k_ws + (size_t)tb * T_LEN * HS;

    for (int jt = 0; jt < njt; ++jt) {
        const int jbase = j0 + jt * 64;
        __syncthreads();   // protect K/V LDS from previous tile's readers
        // ---- stage K (split bf16), 2 slots/thread
        #pragma unroll
        for (int it = 0; it < 2; ++it) {
            const int s  = tid + 256 * it;     // ((jsub*2+kc)*64 + ls)
            const int ls = s & 63;
            const int sc = s >> 6;
            const int jsub = sc >> 1, kc = sc & 1;
            const int jrow = jbase + jsub * 16 + (ls & 15);
            const int koff = kc * 32 + (ls >> 4) * 8;
            const float* src = kbase + (size_t)jrow * HS + koff;
            float v[8];
            *(float4*)&v[0] = *(const float4*)src;
            *(float4*)&v[4] = *(const float4*)(src + 4);
            int4 hi, lo;
            split8(v, hi, lo);
            *(int4*)&Kh[s * 8] = hi;
            *(int4*)&Kl[s * 8] = lo;
        }
        // ---- stage V^T fragments (bf16 RNE), 2 slots/thread
        #pragma unroll
        for (int it = 0; it < 2; ++it) {
            const int s  = tid + 256 * it;     // ((jc*4+nt)*64 + ls)
            const int ls = s & 63;
            const int sc = s >> 6;
            const int jc = sc >> 2, nt = sc & 3;
            const int n  = nt * 16 + (ls & 15);
            const int jcol = jbase + jc * 32 + (ls >> 4) * 8;
            const float* src = vt_ws + (size_t)n * BT + tb * T_LEN + jcol;
            float v[8];
            *(float4*)&v[0] = *(const float4*)src;
            *(float4*)&v[4] = *(const float4*)(src + 4);
            union { unsigned short u[8]; int4 i; } pk;
            #pragma unroll
            for (int i = 0; i < 8; ++i) pk.u[i] = f2bf_rne(v[i]);
            *(int4*)&Vt[s * 8] = pk.i;
        }
        __syncthreads();

        const bool active = (!mask) || (jbase <= rw0 + 15);
        if (active) {
            // ---- QK^T: 4 j-subtiles x (2 k-chunks x 3 split passes)
            f32x4 sacc[4];
            #pragma unroll
            for (int jsub = 0; jsub < 4; ++jsub) {
                f32x4 s = (f32x4)(0.f);
                #pragma unroll
                for (int kc = 0; kc < 2; ++kc) {
                    const bf16x8 kh = *(const bf16x8*)&Kh[((jsub * 2 + kc) * 64 + lane) * 8];
                    const bf16x8 kl = *(const bf16x8*)&Kl[((jsub * 2 + kc) * 64 + lane) * 8];
                    s = __builtin_amdgcn_mfma_f32_16x16x32_bf16(qfh[kc], kh, s, 0, 0, 0);
                    s = __builtin_amdgcn_mfma_f32_16x16x32_bf16(qfh[kc], kl, s, 0, 0, 0);
                    s = __builtin_amdgcn_mfma_f32_16x16x32_bf16(qfl[kc], kh, s, 0, 0, 0);
                }
                sacc[jsub] = s;
            }
            // ---- mask + scale + row max (C-layout: row=quad*4+r, col=l15)
            float sval[4][4], rmax[4];
            #pragma unroll
            for (int r = 0; r < 4; ++r) rmax[r] = -INFINITY;
            #pragma unroll
            for (int jsub = 0; jsub < 4; ++jsub) {
                const int jg = jbase + jsub * 16 + l15;
                #pragma unroll
                for (int r = 0; r < 4; ++r) {
                    const int tg = rw0 + quad * 4 + r;
                    const float vv = (mask && (jg > tg)) ? -INFINITY : 8.0f * sacc[jsub][r];
                    sval[jsub][r] = vv;
                    rmax[r] = fmaxf(rmax[r], vv);
                }
            }
            #pragma unroll
            for (int d = 1; d < 16; d <<= 1)
                #pragma unroll
                for (int r = 0; r < 4; ++r)
                    rmax[r] = fmaxf(rmax[r], __shfl_xor(rmax[r], d));
            float alpha[4], msafe[4];
            #pragma unroll
            for (int r = 0; r < 4; ++r) {
                const float mn = fmaxf(m_r[r], rmax[r]);
                msafe[r] = (mn == -INFINITY) ? 0.f : mn;
                alpha[r] = __expf(m_r[r] - msafe[r]);   // -inf -> 0, never NaN
                m_r[r] = mn;
            }
            // ---- exp -> bf16 P (wave-private LDS) + consistent l sums
            short* Pw = &Pl[w][0];
            float rsum[4] = {0.f, 0.f, 0.f, 0.f};
            #pragma unroll
            for (int jsub = 0; jsub < 4; ++jsub) {
                #pragma unroll
                for (int r = 0; r < 4; ++r) {
                    const float e = __expf(sval[jsub][r] - msafe[r]);
                    const unsigned short eb = f2bf_rne(e);
                    Pw[(quad * 4 + r) * 72 + jsub * 16 + l15] = (short)eb;
                    rsum[r] += bf2f(eb);
                }
            }
            #pragma unroll
            for (int d = 1; d < 16; d <<= 1)
                #pragma unroll
                for (int r = 0; r < 4; ++r)
                    rsum[r] += __shfl_xor(rsum[r], d);
            #pragma unroll
            for (int r = 0; r < 4; ++r)
                l_r[r] = l_r[r] * alpha[r] + rsum[r];
            // ---- rescale O, then PV (P A-frags read back from LDS)
            #pragma unroll
            for (int nt = 0; nt < 4; ++nt)
                #pragma unroll
                for (int r = 0; r < 4; ++r)
                    oacc[nt][r] *= alpha[r];
            bf16x8 pf[2];
            #pragma unroll
            for (int jc = 0; jc < 2; ++jc)
                pf[jc] = *(const bf16x8*)&Pw[l15 * 72 + jc * 32 + quad * 8];
            #pragma unroll
            for (int nt = 0; nt < 4; ++nt) {
                #pragma unroll
                for (int jc = 0; jc < 2; ++jc) {
                    const bf16x8 vf = *(const bf16x8*)&Vt[((jc * 4 + nt) * 64 + lane) * 8];
                    oacc[nt] = __builtin_amdgcn_mfma_f32_16x16x32_bf16(pf[jc], vf, oacc[nt], 0, 0, 0);
                }
            }
        }
    }

    // ---- epilogue: write partials (C-layout rows)
    #pragma unroll
    for (int nt = 0; nt < 4; ++nt)
        #pragma unroll
        for (int r = 0; r < 4; ++r)
            part_O[((size_t)(rowa + r) * NCH + chunk) * HS + nt * 16 + l15] = oacc[nt][r];
    if (l15 == 0) {
        #pragma unroll
        for (int r = 0; r < 4; ++r) {
            float2 ml;
            ml.x = m_r[r];
            ml.y = l_r[r];
            *(float2*)(part_ml + ((size_t)(rowa + r) * NCH + chunk) * 2) = ml;
        }
    }
}

// ---------------------------------------------------------------------------
// Kernel 3: combine chunk partials (UNCHANGED — passing).
// ---------------------------------------------------------------------------
__global__ __launch_bounds__(256) void combine_kernel(
    const float* __restrict__ part_O, const float* __restrict__ part_ml,
    const int* __restrict__ maskp, float* __restrict__ out)
{
    const int f = blockIdx.x * 256 + threadIdx.x;
    const int row = f >> 6;
    const int d = f & 63;
    const int t = row & (T_LEN - 1);
    const int mask = (*maskp != 0);
    const int n = mask ? (t + 1) : T_LEN;
    const int nc = (n + JCH - 1) / JCH;

    float mv[NCH], lv[NCH];
    float M = -INFINITY;
    for (int c = 0; c < nc; ++c) {
        const float2 ml = *(const float2*)(part_ml + ((size_t)row * NCH + c) * 2);
        mv[c] = ml.x; lv[c] = ml.y;
        M = fmaxf(M, ml.x);
    }
    float L = 0.f, O = 0.f;
    for (int c = 0; c < nc; ++c) {
        const float w = __expf(mv[c] - M);
        L += lv[c] * w;
        O = fmaf(part_O[((size_t)row * NCH + c) * HS + d], w, O);
    }
    out[(size_t)row * HS + d] = O / L;
}

// ---------------------------------------------------------------------------
extern "C" void kernel_launch(void* const* d_in, const int* in_sizes, int n_in,
                              void* d_out, int out_size, void* d_ws, size_t ws_size,
                              hipStream_t stream) {
    const float* x  = (const float*)d_in[0];
    const float* Wq = (const float*)d_in[1];
    const float* bq = (const float*)d_in[2];
    const float* Wk = (const float*)d_in[3];
    const float* bk = (const float*)d_in[4];
    const float* Wv = (const float*)d_in[5];
    const int* maskp = (const int*)d_in[6];

    const int BT = in_sizes[0] / D_MODEL;   // 8192

    // ws layout (floats): q,k [BT*64], vt [64*BT], part_O [BT*4*64], part_ml [BT*4*2]
    float* q   = (float*)d_ws;
    float* k   = q + (size_t)BT * HS;
    float* vt  = k + (size_t)BT * HS;
    float* pO  = vt + (size_t)BT * HS;
    float* pml = pO + (size_t)BT * NCH * HS;

    // W split buffers ALIAS part_O (dead until attn_kernel runs, stream-ordered)
    short* Wh = (short*)pO;
    short* Wl = Wh + (size_t)192 * D_MODEL;

    wprep_kernel<<<48, 256, 0, stream>>>(Wq, Wk, Wv, Wh, Wl);
    qkv_kernel<<<BT / 64, 256, 0, stream>>>(x, Wh, Wl, bq, bk, q, k, vt, BT);
    dim3 agrid(BT / 64, NCH);
    attn_kernel<<<agrid, 256, 0, stream>>>(q, k, vt, maskp, pO, pml, BT);
    combine_kernel<<<(BT * HS) / 256, 256, 0, stream>>>(pO, pml, maskp, (float*)d_out);
}

// Round 8
// 155.954 us; speedup vs baseline: 6.3345x; 1.0962x over previous
//
#include <hip/hip_runtime.h>
#include <hip/hip_bf16.h>

// AttentionHead: B=4, T=2048, C=1024, hs=64. All fp32 in/out.
#define D_MODEL 1024
#define HS 64
#define T_LEN 2048
#define JCH 512          // j-chunk width per attention block
#define NCH 4            // max chunks per row = T_LEN/JCH

typedef __attribute__((ext_vector_type(8))) short bf16x8;   // MFMA A/B frag
typedef __attribute__((ext_vector_type(4))) float f32x4;    // MFMA C/D frag

// split 8 floats into hi/lo bf16 (truncation split: residual exact)
__device__ inline void split8(const float* v, int4& hi, int4& lo) {
    union { unsigned short u[8]; int4 v4; } uh, ul;
    #pragma unroll
    for (int i = 0; i < 8; ++i) {
        const unsigned int b = __float_as_uint(v[i]);
        const unsigned short h = (unsigned short)(b >> 16);
        const float r = v[i] - __uint_as_float((unsigned int)h << 16);
        uh.u[i] = h;
        ul.u[i] = (unsigned short)(__float_as_uint(r) >> 16);
    }
    hi = uh.v4; lo = ul.v4;
}

// fp32 -> bf16 round-to-nearest-even (finite inputs only here)
__device__ inline unsigned short f2bf_rne(float f) {
    const unsigned int b = __float_as_uint(f);
    return (unsigned short)((b + 0x7FFFu + ((b >> 16) & 1u)) >> 16);
}
__device__ inline float bf2f(unsigned short h) {
    return __uint_as_float((unsigned int)h << 16);
}

// ---------------------------------------------------------------------------
// Kernel 0: W prep (coalesced) — UNCHANGED from round 7 (passing).
// ---------------------------------------------------------------------------
__global__ __launch_bounds__(256) void wprep_kernel(
    const float* __restrict__ Wq, const float* __restrict__ Wk,
    const float* __restrict__ Wv, short* __restrict__ Wh, short* __restrict__ Wl)
{
    __shared__ float tile[64][69];
    const int tid = threadIdx.x;
    const int kb = blockIdx.x & 15;       // k-block 0..15
    const int m  = blockIdx.x >> 4;       // matrix 0..2
    const float* W = (m == 0) ? Wq : (m == 1) ? Wk : Wv;
    #pragma unroll
    for (int it = 0; it < 4; ++it) {
        const int idx = tid + 256 * it;
        const int kr = idx >> 4, c4 = idx & 15;
        *(float4*)&tile[kr][4 * c4] =
            *(const float4*)(W + (size_t)(kb * 64 + kr) * HS + 4 * c4);
    }
    __syncthreads();
    #pragma unroll
    for (int it = 0; it < 2; ++it) {
        const int s = tid + 256 * it;     // 0..511
        const int n = s >> 3, kc = s & 7;
        float v[8];
        #pragma unroll
        for (int i = 0; i < 8; ++i) v[i] = tile[kc * 8 + i][n];
        int4 hi, lo;
        split8(v, hi, lo);
        const size_t off = (size_t)(m * 64 + n) * D_MODEL + kb * 64 + kc * 8;
        *(int4*)(Wh + off) = hi;
        *(int4*)(Wl + off) = lo;
    }
}

// ---------------------------------------------------------------------------
// Kernel 1: QKV projection via split-bf16 MFMA — RESTRUCTURED.
// Grid (BT/32, 2) = 512 blocks (was 128 -> half the CUs idle, occ 4.6%).
// Block: 32 M x 96 N; wave owns 1 Mtile x 3 Ntiles (12 acc VGPRs).
// K-loop software-pipelined: global loads for k0+32 issue after the
// compute barrier and are consumed at the next write phase, so load
// latency hides under MFMA. LDS ~17 KB -> multiple blocks/CU.
// ---------------------------------------------------------------------------
__global__ __launch_bounds__(256, 2) void qkv_kernel(
    const float* __restrict__ x,
    const short* __restrict__ Wh, const short* __restrict__ Wl,
    const float* __restrict__ bq, const float* __restrict__ bk,
    float* __restrict__ q, float* __restrict__ k, float* __restrict__ vt, int BT)
{
    __shared__ __align__(16) short Ah[2 * 520], Al[2 * 520];
    __shared__ __align__(16) short Bh[6 * 520], Bl[6 * 520];

    const int tid  = threadIdx.x;
    const int r0   = blockIdx.x * 32;
    const int nb   = blockIdx.y;          // N-half: global cols 96*nb ..
    const int wave = tid >> 6;
    const int lane = tid & 63;
    const int mt_w = wave >> 1;           // wave's Mtile (0..1)
    const int nt0  = (wave & 1) * 3;      // wave's first local ntile

    f32x4 acc[3];
    #pragma unroll
    for (int j = 0; j < 3; ++j) acc[j] = (f32x4)(0.f);

    // staging roles: tid>=128 -> one A slot + one B slot; tid<128 -> two B slots
    const bool doA = (tid >= 128);
    const int  au  = tid & 127;           // A slot index when doA
    const int  amt = au >> 6;             // A Mtile
    const int  aln = au & 63;             // A frag lane slot
    const float* axsrc =
        x + (size_t)(r0 + amt * 16 + (aln & 15)) * D_MODEL + (aln >> 4) * 8;

    const int b0nt = tid >> 6;            // B slot 0: local ntile 0..3
    const int b0ln = tid & 63;
    const size_t b0off =
        (size_t)(nb * 96 + b0nt * 16 + (b0ln & 15)) * D_MODEL + (b0ln >> 4) * 8;
    const int b1nt = 4 + (tid >> 6);      // B slot 1 (tid<128): ntile 4..5
    const int b1ln = tid & 63;
    const size_t b1off =
        (size_t)(nb * 96 + b1nt * 16 + (b1ln & 15)) * D_MODEL + (b1ln >> 4) * 8;

    // preload k0 = 0
    float4 a0v, a1v;
    int4 b0h, b0l, b1h, b1l;
    if (doA) {
        a0v = *(const float4*)(axsrc);
        a1v = *(const float4*)(axsrc + 4);
    }
    b0h = *(const int4*)(Wh + b0off);
    b0l = *(const int4*)(Wl + b0off);
    if (!doA) {
        b1h = *(const int4*)(Wh + b1off);
        b1l = *(const int4*)(Wl + b1off);
    }

    for (int k0 = 0; k0 < D_MODEL; k0 += 32) {
        __syncthreads();                  // prior iteration's LDS readers done
        // ---- write staged registers to LDS
        if (doA) {
            float xv[8];
            *(float4*)&xv[0] = a0v;
            *(float4*)&xv[4] = a1v;
            int4 hi, lo;
            split8(xv, hi, lo);
            *(int4*)&Ah[amt * 520 + aln * 8] = hi;
            *(int4*)&Al[amt * 520 + aln * 8] = lo;
        }
        *(int4*)&Bh[b0nt * 520 + b0ln * 8] = b0h;
        *(int4*)&Bl[b0nt * 520 + b0ln * 8] = b0l;
        if (!doA) {
            *(int4*)&Bh[b1nt * 520 + b1ln * 8] = b1h;
            *(int4*)&Bl[b1nt * 520 + b1ln * 8] = b1l;
        }
        __syncthreads();                  // LDS ready
        // ---- preload next k-chunk (latency hides under MFMA below)
        const int kn = k0 + 32;
        if (kn < D_MODEL) {
            if (doA) {
                a0v = *(const float4*)(axsrc + kn);
                a1v = *(const float4*)(axsrc + kn + 4);
            }
            b0h = *(const int4*)(Wh + b0off + kn);
            b0l = *(const int4*)(Wl + b0off + kn);
            if (!doA) {
                b1h = *(const int4*)(Wh + b1off + kn);
                b1l = *(const int4*)(Wl + b1off + kn);
            }
        }
        // ---- MFMA: 1 Mtile x 3 Ntiles x 3 split passes
        const bf16x8 afh = *(const bf16x8*)&Ah[mt_w * 520 + lane * 8];
        const bf16x8 afl = *(const bf16x8*)&Al[mt_w * 520 + lane * 8];
        #pragma unroll
        for (int j = 0; j < 3; ++j) {
            const int nt = nt0 + j;
            const bf16x8 bfh = *(const bf16x8*)&Bh[nt * 520 + lane * 8];
            const bf16x8 bfl = *(const bf16x8*)&Bl[nt * 520 + lane * 8];
            acc[j] = __builtin_amdgcn_mfma_f32_16x16x32_bf16(afh, bfh, acc[j], 0, 0, 0);
            acc[j] = __builtin_amdgcn_mfma_f32_16x16x32_bf16(afh, bfl, acc[j], 0, 0, 0);
            acc[j] = __builtin_amdgcn_mfma_f32_16x16x32_bf16(afl, bfh, acc[j], 0, 0, 0);
        }
    }

    // ---- epilogue: C/D layout col=lane&15, row=(lane>>4)*4+reg
    const int rowb = r0 + mt_w * 16 + (lane >> 4) * 4;
    #pragma unroll
    for (int j = 0; j < 3; ++j) {
        const int c = nb * 96 + (nt0 + j) * 16 + (lane & 15);
        if (c < 64) {
            const float bias = bq[c];
            #pragma unroll
            for (int r = 0; r < 4; ++r)
                q[(size_t)(rowb + r) * HS + c] = acc[j][r] + bias;
        } else if (c < 128) {
            const float bias = bk[c - 64];
            #pragma unroll
            for (int r = 0; r < 4; ++r)
                k[(size_t)(rowb + r) * HS + (c - 64)] = acc[j][r] + bias;
        } else {
            float4 o;
            o.x = acc[j][0]; o.y = acc[j][1]; o.z = acc[j][2]; o.w = acc[j][3];
            *(float4*)(vt + (size_t)(c - 128) * BT + rowb) = o;
        }
    }
}

// ---------------------------------------------------------------------------
// Kernel 2: flash-style attention via MFMA — UNCHANGED from round 7 (passing).
// ---------------------------------------------------------------------------
__global__ __launch_bounds__(256) void attn_kernel(
    const float* __restrict__ q_ws, const float* __restrict__ k_ws,
    const float* __restrict__ vt_ws, const int* __restrict__ maskp,
    float* __restrict__ part_O, float* __restrict__ part_ml, int BT)
{
    __shared__ __align__(16) short Kh[4096], Kl[4096];
    __shared__ __align__(16) short Vt[4096];
    __shared__ __align__(16) short Pl[4][16 * 72];

    const int tile  = blockIdx.x;
    const int chunk = blockIdx.y;
    const int r0 = tile * 64;
    const int tb = r0 / T_LEN;
    const int t0 = r0 - tb * T_LEN;
    const int mask = (*maskp != 0);
    const int n_max = mask ? (t0 + 64) : T_LEN;
    const int j0 = chunk * JCH;
    if (j0 >= n_max) return;
    const int hi_j = min(j0 + JCH, n_max);
    const int njt = (hi_j - j0 + 63) >> 6;

    const int tid  = threadIdx.x;
    const int w    = tid >> 6;
    const int lane = tid & 63;
    const int quad = lane >> 4;
    const int l15  = lane & 15;
    const int rw0  = t0 + 16 * w;
    const int rowa = r0 + 16 * w + quad * 4;

    bf16x8 qfh[2], qfl[2];
    {
        const float* qrow = q_ws + (size_t)(r0 + 16 * w + l15) * HS + quad * 8;
        #pragma unroll
        for (int kc = 0; kc < 2; ++kc) {
            float v[8];
            *(float4*)&v[0] = *(const float4*)(qrow + kc * 32);
            *(float4*)&v[4] = *(const float4*)(qrow + kc * 32 + 4);
            union { int4 i; bf16x8 b; } ch, cl;
            split8(v, ch.i, cl.i);
            qfh[kc] = ch.b;
            qfl[kc] = cl.b;
        }
    }

    f32x4 oacc[4];
    #pragma unroll
    for (int nt = 0; nt < 4; ++nt) oacc[nt] = (f32x4)(0.f);
    float m_r[4] = {-INFINITY, -INFINITY, -INFINITY, -INFINITY};
    float l_r[4] = {0.f, 0.f, 0.f, 0.f};

    const float* kbase = k_ws + (size_t)tb * T_LEN * HS;

    for (int jt = 0; jt < njt; ++jt) {
        const int jbase = j0 + jt * 64;
        __syncthreads();
        #pragma unroll
        for (int it = 0; it < 2; ++it) {
            const int s  = tid + 256 * it;
            const int ls = s & 63;
            const int sc = s >> 6;
            const int jsub = sc >> 1, kc = sc & 1;
            const int jrow = jbase + jsub * 16 + (ls & 15);
            const int koff = kc * 32 + (ls >> 4) * 8;
            const float* src = kbase + (size_t)jrow * HS + koff;
            float v[8];
            *(float4*)&v[0] = *(const float4*)src;
            *(float4*)&v[4] = *(const float4*)(src + 4);
            int4 hi, lo;
            split8(v, hi, lo);
            *(int4*)&Kh[s * 8] = hi;
            *(int4*)&Kl[s * 8] = lo;
        }
        #pragma unroll
        for (int it = 0; it < 2; ++it) {
            const int s  = tid + 256 * it;
            const int ls = s & 63;
            const int sc = s >> 6;
            const int jc = sc >> 2, nt = sc & 3;
            const int n  = nt * 16 + (ls & 15);
            const int jcol = jbase + jc * 32 + (ls >> 4) * 8;
            const float* src = vt_ws + (size_t)n * BT + tb * T_LEN + jcol;
            float v[8];
            *(float4*)&v[0] = *(const float4*)src;
            *(float4*)&v[4] = *(const float4*)(src + 4);
            union { unsigned short u[8]; int4 i; } pk;
            #pragma unroll
            for (int i = 0; i < 8; ++i) pk.u[i] = f2bf_rne(v[i]);
            *(int4*)&Vt[s * 8] = pk.i;
        }
        __syncthreads();

        const bool active = (!mask) || (jbase <= rw0 + 15);
        if (active) {
            f32x4 sacc[4];
            #pragma unroll
            for (int jsub = 0; jsub < 4; ++jsub) {
                f32x4 s = (f32x4)(0.f);
                #pragma unroll
                for (int kc = 0; kc < 2; ++kc) {
                    const bf16x8 kh = *(const bf16x8*)&Kh[((jsub * 2 + kc) * 64 + lane) * 8];
                    const bf16x8 kl = *(const bf16x8*)&Kl[((jsub * 2 + kc) * 64 + lane) * 8];
                    s = __builtin_amdgcn_mfma_f32_16x16x32_bf16(qfh[kc], kh, s, 0, 0, 0);
                    s = __builtin_amdgcn_mfma_f32_16x16x32_bf16(qfh[kc], kl, s, 0, 0, 0);
                    s = __builtin_amdgcn_mfma_f32_16x16x32_bf16(qfl[kc], kh, s, 0, 0, 0);
                }
                sacc[jsub] = s;
            }
            float sval[4][4], rmax[4];
            #pragma unroll
            for (int r = 0; r < 4; ++r) rmax[r] = -INFINITY;
            #pragma unroll
            for (int jsub = 0; jsub < 4; ++jsub) {
                const int jg = jbase + jsub * 16 + l15;
                #pragma unroll
                for (int r = 0; r < 4; ++r) {
                    const int tg = rw0 + quad * 4 + r;
                    const float vv = (mask && (jg > tg)) ? -INFINITY : 8.0f * sacc[jsub][r];
                    sval[jsub][r] = vv;
                    rmax[r] = fmaxf(rmax[r], vv);
                }
            }
            #pragma unroll
            for (int d = 1; d < 16; d <<= 1)
                #pragma unroll
                for (int r = 0; r < 4; ++r)
                    rmax[r] = fmaxf(rmax[r], __shfl_xor(rmax[r], d));
            float alpha[4], msafe[4];
            #pragma unroll
            for (int r = 0; r < 4; ++r) {
                const float mn = fmaxf(m_r[r], rmax[r]);
                msafe[r] = (mn == -INFINITY) ? 0.f : mn;
                alpha[r] = __expf(m_r[r] - msafe[r]);
                m_r[r] = mn;
            }
            short* Pw = &Pl[w][0];
            float rsum[4] = {0.f, 0.f, 0.f, 0.f};
            #pragma unroll
            for (int jsub = 0; jsub < 4; ++jsub) {
                #pragma unroll
                for (int r = 0; r < 4; ++r) {
                    const float e = __expf(sval[jsub][r] - msafe[r]);
                    const unsigned short eb = f2bf_rne(e);
                    Pw[(quad * 4 + r) * 72 + jsub * 16 + l15] = (short)eb;
                    rsum[r] += bf2f(eb);
                }
            }
            #pragma unroll
            for (int d = 1; d < 16; d <<= 1)
                #pragma unroll
                for (int r = 0; r < 4; ++r)
                    rsum[r] += __shfl_xor(rsum[r], d);
            #pragma unroll
            for (int r = 0; r < 4; ++r)
                l_r[r] = l_r[r] * alpha[r] + rsum[r];
            #pragma unroll
            for (int nt = 0; nt < 4; ++nt)
                #pragma unroll
                for (int r = 0; r < 4; ++r)
                    oacc[nt][r] *= alpha[r];
            bf16x8 pf[2];
            #pragma unroll
            for (int jc = 0; jc < 2; ++jc)
                pf[jc] = *(const bf16x8*)&Pw[l15 * 72 + jc * 32 + quad * 8];
            #pragma unroll
            for (int nt = 0; nt < 4; ++nt) {
                #pragma unroll
                for (int jc = 0; jc < 2; ++jc) {
                    const bf16x8 vf = *(const bf16x8*)&Vt[((jc * 4 + nt) * 64 + lane) * 8];
                    oacc[nt] = __builtin_amdgcn_mfma_f32_16x16x32_bf16(pf[jc], vf, oacc[nt], 0, 0, 0);
                }
            }
        }
    }

    #pragma unroll
    for (int nt = 0; nt < 4; ++nt)
        #pragma unroll
        for (int r = 0; r < 4; ++r)
            part_O[((size_t)(rowa + r) * NCH + chunk) * HS + nt * 16 + l15] = oacc[nt][r];
    if (l15 == 0) {
        #pragma unroll
        for (int r = 0; r < 4; ++r) {
            float2 ml;
            ml.x = m_r[r];
            ml.y = l_r[r];
            *(float2*)(part_ml + ((size_t)(rowa + r) * NCH + chunk) * 2) = ml;
        }
    }
}

// ---------------------------------------------------------------------------
// Kernel 3: combine chunk partials — UNCHANGED (passing).
// ---------------------------------------------------------------------------
__global__ __launch_bounds__(256) void combine_kernel(
    const float* __restrict__ part_O, const float* __restrict__ part_ml,
    const int* __restrict__ maskp, float* __restrict__ out)
{
    const int f = blockIdx.x * 256 + threadIdx.x;
    const int row = f >> 6;
    const int d = f & 63;
    const int t = row & (T_LEN - 1);
    const int mask = (*maskp != 0);
    const int n = mask ? (t + 1) : T_LEN;
    const int nc = (n + JCH - 1) / JCH;

    float mv[NCH], lv[NCH];
    float M = -INFINITY;
    for (int c = 0; c < nc; ++c) {
        const float2 ml = *(const float2*)(part_ml + ((size_t)row * NCH + c) * 2);
        mv[c] = ml.x; lv[c] = ml.y;
        M = fmaxf(M, ml.x);
    }
    float L = 0.f, O = 0.f;
    for (int c = 0; c < nc; ++c) {
        const float w = __expf(mv[c] - M);
        L += lv[c] * w;
        O = fmaf(part_O[((size_t)row * NCH + c) * HS + d], w, O);
    }
    out[(size_t)row * HS + d] = O / L;
}

// ---------------------------------------------------------------------------
extern "C" void kernel_launch(void* const* d_in, const int* in_sizes, int n_in,
                              void* d_out, int out_size, void* d_ws, size_t ws_size,
                              hipStream_t stream) {
    const float* x  = (const float*)d_in[0];
    const float* Wq = (const float*)d_in[1];
    const float* bq = (const float*)d_in[2];
    const float* Wk = (const float*)d_in[3];
    const float* bk = (const float*)d_in[4];
    const float* Wv = (const float*)d_in[5];
    const int* maskp = (const int*)d_in[6];

    const int BT = in_sizes[0] / D_MODEL;   // 8192

    // ws layout (floats): q,k [BT*64], vt [64*BT], part_O [BT*4*64], part_ml [BT*4*2]
    float* q   = (float*)d_ws;
    float* k   = q + (size_t)BT * HS;
    float* vt  = k + (size_t)BT * HS;
    float* pO  = vt + (size_t)BT * HS;
    float* pml = pO + (size_t)BT * NCH * HS;

    // W split buffers ALIAS part_O (dead until attn_kernel runs, stream-ordered)
    short* Wh = (short*)pO;
    short* Wl = Wh + (size_t)192 * D_MODEL;

    wprep_kernel<<<48, 256, 0, stream>>>(Wq, Wk, Wv, Wh, Wl);
    dim3 qgrid(BT / 32, 2);
    qkv_kernel<<<qgrid, 256, 0, stream>>>(x, Wh, Wl, bq, bk, q, k, vt, BT);
    dim3 agrid(BT / 64, NCH);
    attn_kernel<<<agrid, 256, 0, stream>>>(q, k, vt, maskp, pO, pml, BT);
    combine_kernel<<<(BT * HS) / 256, 256, 0, stream>>>(pO, pml, maskp, (float*)d_out);
}